// Round 19
// baseline (342.722 us; speedup 1.0000x reference)
//
#include <hip/hip_runtime.h>

typedef __attribute__((ext_vector_type(4))) float f32x4;
typedef __attribute__((ext_vector_type(16))) float f32x16;
typedef __attribute__((ext_vector_type(8))) short s16x8;
typedef __attribute__((ext_vector_type(4))) unsigned short u16x4;
typedef __attribute__((ext_vector_type(8))) unsigned short u16x8;

#define DEVINL __device__ __forceinline__

constexpr int Bb = 2;
constexpr int Ss = 2048;
constexpr int Hh = 2048;
constexpr int NH = 16;
constexpr int HD = 128;
constexpr float ATT_SCALE = 0.08838834764831845f;   // 128^-0.5
constexpr float CEXP = ATT_SCALE * 1.44269504089f;  // scale * log2(e)
constexpr float INV_SCALE = 11.313708498984761f;    // 1/scale
constexpr float RAW_THR = 90.50966799f;             // 8/scale (defer-max threshold)

DEVINL unsigned short f2bf(float f) {
    unsigned u = __float_as_uint(f);
    u += 0x7FFFu + ((u >> 16) & 1u);
    return (unsigned short)(u >> 16);
}
DEVINL float bf2f(unsigned short h) { return __uint_as_float(((unsigned)h) << 16); }
DEVINL float fexp2(float x) { return __builtin_amdgcn_exp2f(x); }

// global -> LDS direct (16B per lane). Dest must be linear in lane order.
DEVINL void gl16(const void* g, void* l) {
    __builtin_amdgcn_global_load_lds((const __attribute__((address_space(1))) void*)g,
                                     (__attribute__((address_space(3))) void*)l, 16, 0, 0);
}

// ---------------- mask zero-scan (full coverage: 8192 blocks x 1024 floats) ----------
__global__ void scan_mask_k(const float* __restrict__ m, int* __restrict__ flag) {
    size_t i = ((size_t)blockIdx.x * 256 + threadIdx.x) * 4;
    f32x4 v = *(const f32x4*)(m + i);
    int any = (v[0] != 0.f) || (v[1] != 0.f) || (v[2] != 0.f) || (v[3] != 0.f);
    if (__any(any)) { if ((threadIdx.x & 63) == 0) atomicOr(flag, 1); }
}

// ---------------- fp32 -> bf16 convert (hidden) ----------------
__global__ void convH_k(const float* __restrict__ x, unsigned short* __restrict__ y) {
    size_t i = (size_t)blockIdx.x * 256 + threadIdx.x;
    f32x4 a = *(const f32x4*)(x + i * 8);
    f32x4 b = *(const f32x4*)(x + i * 8 + 4);
    u16x8 o;
    o[0] = f2bf(a[0]); o[1] = f2bf(a[1]); o[2] = f2bf(a[2]); o[3] = f2bf(a[3]);
    o[4] = f2bf(b[0]); o[5] = f2bf(b[1]); o[6] = f2bf(b[2]); o[7] = f2bf(b[3]);
    *(u16x8*)(y + i * 8) = o;
}

// ---------------- fp32 -> bf16 transpose (weights: W[R][C] -> Wt[C][R]) ----------------
__global__ void convT_k(const float* __restrict__ W, unsigned short* __restrict__ Wt,
                        int R, int C) {
    __shared__ float tile[32][33];
    int c0 = blockIdx.x * 32, r0 = blockIdx.y * 32;
    int t = threadIdx.x;
    int rr = t >> 3, cc = (t & 7) * 4;
    f32x4 v = *(const f32x4*)(W + (size_t)(r0 + rr) * C + c0 + cc);
    tile[rr][cc + 0] = v[0]; tile[rr][cc + 1] = v[1];
    tile[rr][cc + 2] = v[2]; tile[rr][cc + 3] = v[3];
    __syncthreads();
    u16x4 o;
    o[0] = f2bf(tile[cc + 0][rr]); o[1] = f2bf(tile[cc + 1][rr]);
    o[2] = f2bf(tile[cc + 2][rr]); o[3] = f2bf(tile[cc + 3][rr]);
    *(u16x4*)(Wt + (size_t)(c0 + rr) * R + r0 + cc) = o;
}

// ====== 128x128 GEMM, BK=64 dbuf, 64KB LDS -> 2 blocks/CU, overlapped staging ======
// 4 waves (2x2), wave 64x64 (4x4 frags 16x16x32). R3-proven LDS layout: 128B rows,
// XOR swizzle byte = row*128 + (col16 ^ ((row&7)<<4)) -> 0 bank conflicts (measured).
// Rectangle XCD swizzle. MODE 0 (QKV): fused RoPE + V written transposed to Vt.
template<int MODE>
__global__ __launch_bounds__(256, 2)
void gemm128_k(const unsigned short* __restrict__ A, const unsigned short* __restrict__ Bt,
               float* __restrict__ Cf, unsigned short* __restrict__ Cb,
               unsigned short* __restrict__ VtOut,
               int M, int N, int K, int rm, int rn, int snx) {
    __shared__ char lds[65536];
    int t = threadIdx.x, w = t >> 6, ln = t & 63, lr = ln & 15, lg = ln >> 4;
    int wr = w >> 1, wc = w & 1;
    int f = blockIdx.x;
    int xcd = f & 7, i0 = f >> 3;
    int mb = (xcd / snx) * rm + i0 % rm;
    int nb = (xcd % snx) * rn + i0 / rm;
    int m0 = mb * 128, n0 = nb * 128;
    const char* Ab = (const char*)A;
    const char* Bbp = (const char*)Bt;

    f32x4 acc[4][4];
#pragma unroll
    for (int i = 0; i < 4; ++i)
#pragma unroll
        for (int j = 0; j < 4; ++j) { acc[i][j][0] = 0.f; acc[i][j][1] = 0.f; acc[i][j][2] = 0.f; acc[i][j][3] = 0.f; }

    // stage K-tile kt into buffer buf: A 16KB + B 16KB, 8 gl16/thread,
    // lane-linear dest, inverse-swizzled source column slot.
    auto STAGE = [&](int buf, int kt) {
        char* dA = lds + buf * 32768;
        char* dB = dA + 16384;
        size_t kb = ((size_t)kt * 64) * 2;
#pragma unroll
        for (int ld = 0; ld < 4; ++ld) {
            int ci = ld * 256 + t;
            int row = ci >> 3, cb = (ci & 7) << 4;
            int sc = cb ^ ((row & 7) << 4);
            gl16(Ab + ((size_t)(m0 + row) * K) * 2 + kb + sc, dA + ci * 16);
            gl16(Bbp + ((size_t)(n0 + row) * K) * 2 + kb + sc, dB + ci * 16);
        }
    };

    const int NT = K >> 6;
    STAGE(0, 0);
    asm volatile("s_waitcnt vmcnt(0)" ::: "memory");
    __builtin_amdgcn_s_barrier();

    for (int kt = 0; kt < NT; ++kt) {
        int cur = kt & 1;
        if (kt + 1 < NT) STAGE(cur ^ 1, kt + 1);   // uniform; hides under compute
        const char* As = lds + cur * 32768;
        const char* Bs = As + 16384;
#pragma unroll
        for (int kc = 0; kc < 2; ++kc) {
            s16x8 af[4], bfr[4];
#pragma unroll
            for (int i = 0; i < 4; ++i) {
                int rowa = wr * 64 + i * 16 + lr;
                af[i] = *(const s16x8*)(As + rowa * 128 + ((kc * 64 + lg * 16) ^ ((rowa & 7) << 4)));
                int rowb = wc * 64 + i * 16 + lr;
                bfr[i] = *(const s16x8*)(Bs + rowb * 128 + ((kc * 64 + lg * 16) ^ ((rowb & 7) << 4)));
            }
            __builtin_amdgcn_s_setprio(1);
#pragma unroll
            for (int i = 0; i < 4; ++i)
#pragma unroll
                for (int j = 0; j < 4; ++j)
                    acc[i][j] = __builtin_amdgcn_mfma_f32_16x16x32_bf16(af[i], bfr[j], acc[i][j], 0, 0, 0);
            __builtin_amdgcn_s_setprio(0);
        }
        // next tile's loads landed under compute; drain + 1 barrier per tile
        asm volatile("s_waitcnt vmcnt(0)" ::: "memory");
        __builtin_amdgcn_s_barrier();
    }

    if (MODE == 0 && n0 >= 4096) {
        // V columns: write transposed directly into Vt[bh=(b*16+h)][d][s]
#pragma unroll
        for (int i = 0; i < 4; ++i)
#pragma unroll
            for (int j = 0; j < 4; ++j) {
                int vcol = n0 - 4096 + wc * 64 + j * 16 + lr;   // 0..2047
                int h = vcol >> 7, d = vcol & 127;
                int gr = m0 + wr * 64 + i * 16 + lg * 4;
                int bb = gr >> 11, si = gr & 2047;
                u16x4 o;
                o[0] = f2bf(acc[i][j][0]); o[1] = f2bf(acc[i][j][1]);
                o[2] = f2bf(acc[i][j][2]); o[3] = f2bf(acc[i][j][3]);
                *(u16x4*)(VtOut + ((size_t)(bb * 16 + h) * 128 + d) * 2048 + si) = o;
            }
        return;
    }

    // fused RoPE (QKV only, n0 < 4096): wc==0 waves hold the rotary pair
    // (j=0 -> d=lr, j=1 -> d=lr+16) of each head's first half.
    if (MODE == 0 && wc == 0) {
        float invf = fexp2((float)lr * -0.83048202372f); // 10000^(-lr/16)
#pragma unroll
        for (int i = 0; i < 4; ++i)
#pragma unroll
            for (int r = 0; r < 4; ++r) {
                int srow = (m0 + wr * 64 + i * 16 + lg * 4 + r) & (Ss - 1);
                float sn, cs;
                sincosf((float)srow * invf, &sn, &cs);
                float x1 = acc[i][0][r], x2 = acc[i][1][r];
                acc[i][0][r] = x1 * cs - x2 * sn;
                acc[i][1][r] = x2 * cs + x1 * sn;
            }
    }

    // epilogue: C/D layout col=l&15, row=(l>>4)*4+r
#pragma unroll
    for (int i = 0; i < 4; ++i)
#pragma unroll
        for (int j = 0; j < 4; ++j)
#pragma unroll
            for (int r = 0; r < 4; ++r) {
                int gr = m0 + wr * 64 + i * 16 + lg * 4 + r;
                int gc = n0 + wc * 64 + j * 16 + lr;
                float vv = acc[i][j][r];
                if (MODE == 1) Cf[(size_t)gr * N + gc] = vv;
                else           Cb[(size_t)gr * N + gc] = f2bf(vv);
            }
}

// ---------------- flash attention (R19: 512 blocks x 4 waves, cross-block overlap) ---
// 512 blocks (32 bh x 16 qt), 256 thr = 4 waves x 32 q. LDS 64KB -> 2 blocks/CU:
// two independent barrier domains per CU; one block's staging drain hides under
// the other's compute (R16's proven mechanism). Math identical to R15/R18.
__global__ __launch_bounds__(256)
void attn_k(const unsigned short* __restrict__ qkv, const unsigned short* __restrict__ Vt,
            const float* __restrict__ mask, unsigned short* __restrict__ ctxb,
            const int* __restrict__ flag) {
    __shared__ char ldsK[2][16384];            // [64 kk][128 d] bf16, 4-bit swizzle
    __shared__ char ldsV[2][16384];            // [128 d][64 kk] bf16, 3-bit swizzle
    int f = blockIdx.x;
    int swzb = (f & 7) * 64 + (f >> 3);        // XCD swizzle: 512 blocks, 64/XCD
    int bh = swzb >> 4, qt = swzb & 15;
    int b = bh >> 4, h = bh & 15;
    int t = threadIdx.x, w = t >> 6, ln = t & 63;
    int q5 = ln & 31, lg5 = ln >> 5;
    int useMask = *flag;
    int qb = qt * 128 + w * 32;                // wave's 32 q-rows
    const char* qkvB = (const char*)qkv;
    const char* VtB = (const char*)Vt;

    auto STAGE = [&](int buf, int kk0s) {
#pragma unroll
        for (int c = 0; c < 4; ++c) {
            int ci = c * 256 + t;
            int krow = ci >> 4, kcb = (ci & 15) << 4;
            gl16(qkvB + (((size_t)(b * Ss + kk0s + krow)) * 6144 + 2048 + h * 128) * 2 + (kcb ^ ((krow & 15) << 4)),
                 ldsK[buf] + ci * 16);
        }
#pragma unroll
        for (int c = 0; c < 4; ++c) {
            int ci = c * 256 + t;
            int vrow = ci >> 3, vcb = (ci & 7) << 4;
            gl16(VtB + (((size_t)(bh * 128 + vrow)) * 2048 + kk0s) * 2 + (vcb ^ ((vrow & 7) << 4)),
                 ldsV[buf] + ci * 16);
        }
    };

    // Q fragments (B-operand): qf[dc] = Q[q=qb+q5][d = dc*16 + lg5*8 + e]
    s16x8 qf[8];
    size_t qrow = ((size_t)(b * Ss + qb + q5)) * 6144 + h * 128;
#pragma unroll
    for (int dc = 0; dc < 8; ++dc) qf[dc] = *(const s16x8*)(qkv + qrow + dc * 16 + lg5 * 8);

    float mr = -3e38f, lsum = 0.f;             // per-lane state for q = qb + q5
    f32x16 ctx[4];
#pragma unroll
    for (int dt = 0; dt < 4; ++dt)
#pragma unroll
        for (int r = 0; r < 16; ++r) ctx[dt][r] = 0.f;
    const float* mrow = mask + (size_t)b * Ss * Ss;

    STAGE(0, 0);
    asm volatile("s_waitcnt vmcnt(0)" ::: "memory");
    __builtin_amdgcn_s_barrier();

    for (int tix = 0; tix < 32; ++tix) {
        int kk0 = tix * 64;
        int cur = tix & 1;
        if (kk0 + 64 < Ss) STAGE(cur ^ 1, kk0 + 64);   // uniform; hides under compute

        f32x16 st[2];
#pragma unroll
        for (int n = 0; n < 2; ++n) {
            f32x16 sacc;
#pragma unroll
            for (int r = 0; r < 16; ++r) sacc[r] = 0.f;
            int krow = n * 32 + q5;
            const char* kb = ldsK[cur] + krow * 256;
            int sw = krow & 15;
            __builtin_amdgcn_s_setprio(1);
#pragma unroll
            for (int dc = 0; dc < 8; ++dc) {
                s16x8 kf = *(const s16x8*)(kb + (((dc * 2 + lg5) ^ sw) << 4));
                sacc = __builtin_amdgcn_mfma_f32_32x32x16_bf16(kf, qf[dc], sacc, 0, 0, 0);
            }
            __builtin_amdgcn_s_setprio(0);
            st[n] = sacc;
        }
        if (useMask) {
#pragma unroll
            for (int n = 0; n < 2; ++n)
#pragma unroll
                for (int r = 0; r < 16; ++r) {
                    int kk = n * 32 + (r & 3) + 8 * (r >> 2) + 4 * lg5;
                    st[n][r] += mrow[(size_t)(qb + q5) * Ss + kk0 + kk] * INV_SCALE;
                }
        }
        float pmax = st[0][0];
#pragma unroll
        for (int n = 0; n < 2; ++n)
#pragma unroll
            for (int r = 0; r < 16; ++r) pmax = fmaxf(pmax, st[n][r]);
        pmax = fmaxf(pmax, __shfl_xor(pmax, 32));
        bool need = pmax > mr + RAW_THR;
        if (__any(need)) {
            float mn = fmaxf(mr, pmax);
            float al = fexp2((mr - mn) * CEXP);
            mr = mn;
            lsum *= al;
#pragma unroll
            for (int dt = 0; dt < 4; ++dt)
#pragma unroll
                for (int r = 0; r < 16; ++r)
                    ctx[dt][r] *= __shfl(al, (r & 3) + 8 * (r >> 2) + 4 * lg5);
        }
        float mC = mr * CEXP;
        float rs = 0.f;
#pragma unroll
        for (int n = 0; n < 2; ++n)
#pragma unroll
            for (int r = 0; r < 16; ++r) {
                float p = fexp2(st[n][r] * CEXP - mC);
                rs += p;
                st[n][r] = p;
            }
        rs += __shfl_xor(rs, 32);
        lsum += rs;
        // P -> A-fragments in registers (no LDS roundtrip): pack pairs, exchange
        // complementary kk-half via shfl_xor(32), select by lg5.
        s16x8 paf[4];
#pragma unroll
        for (int c = 0; c < 4; ++c) {
            const f32x16 sv = st[c >> 1];
            const int cc = (c & 1) * 8;
            unsigned loA = (unsigned)f2bf(sv[cc + 0]) | ((unsigned)f2bf(sv[cc + 1]) << 16);
            unsigned loB = (unsigned)f2bf(sv[cc + 2]) | ((unsigned)f2bf(sv[cc + 3]) << 16);
            unsigned hiA = (unsigned)f2bf(sv[cc + 4]) | ((unsigned)f2bf(sv[cc + 5]) << 16);
            unsigned hiB = (unsigned)f2bf(sv[cc + 6]) | ((unsigned)f2bf(sv[cc + 7]) << 16);
            unsigned sendA = lg5 ? loA : hiA;
            unsigned sendB = lg5 ? loB : hiB;
            unsigned recvA = (unsigned)__shfl_xor((int)sendA, 32);
            unsigned recvB = (unsigned)__shfl_xor((int)sendB, 32);
            union { s16x8 v; unsigned u[4]; } pu;
            pu.u[0] = lg5 ? recvA : loA;
            pu.u[1] = lg5 ? recvB : loB;
            pu.u[2] = lg5 ? hiA : recvA;
            pu.u[3] = lg5 ? hiB : recvB;
            paf[c] = pu.v;
        }
        // PV: ctx[q][d] += P[q][kk] * V[kk][d]
#pragma unroll
        for (int dt = 0; dt < 4; ++dt) {
            int vrow = dt * 32 + q5;
            const char* vb = ldsV[cur] + vrow * 128;
            int swv = vrow & 7;
            __builtin_amdgcn_s_setprio(1);
#pragma unroll
            for (int c = 0; c < 4; ++c) {
                s16x8 vf = *(const s16x8*)(vb + (((c * 2 + lg5) ^ swv) << 4));
                ctx[dt] = __builtin_amdgcn_mfma_f32_32x32x16_bf16(paf[c], vf, ctx[dt], 0, 0, 0);
            }
            __builtin_amdgcn_s_setprio(0);
        }
        asm volatile("s_waitcnt vmcnt(0)" ::: "memory");
        __builtin_amdgcn_s_barrier();
    }
    // epilogue: divide by lsum[q_r], write ctx bf16 (lanes 0..31 = consecutive d)
#pragma unroll
    for (int r = 0; r < 16; ++r) {
        int qr = (r & 3) + 8 * (r >> 2) + 4 * lg5;
        float li = 1.f / __shfl(lsum, qr);
        size_t base = ((size_t)(b * Ss + qb + qr)) * Hh + h * 128 + q5;
#pragma unroll
        for (int dt = 0; dt < 4; ++dt)
            ctxb[base + dt * 32] = f2bf(ctx[dt][r] * li);
    }
}

extern "C" void kernel_launch(void* const* d_in, const int* in_sizes, int n_in,
                              void* d_out, int out_size, void* d_ws, size_t ws_size,
                              hipStream_t stream) {
    (void)in_sizes; (void)n_in; (void)out_size; (void)ws_size;
    const float* hidden = (const float*)d_in[0];
    const float* mask   = (const float*)d_in[1];
    const float* Wqkv   = (const float*)d_in[2];
    const float* Wout   = (const float*)d_in[3];
    float* out = (float*)d_out;

    char* ws = (char*)d_ws;
    size_t off = 0;
    auto alloc = [&](size_t bytes) { char* p = ws + off; off += (bytes + 255) & ~(size_t)255; return p; };
    unsigned short* hbf   = (unsigned short*)alloc((size_t)8388608 * 2);   // hidden bf16; later aliased as ctx
    unsigned short* wqkvT = (unsigned short*)alloc((size_t)12582912 * 2);  // (6144,2048)
    unsigned short* woutT = (unsigned short*)alloc((size_t)4194304 * 2);   // (2048,2048)
    unsigned short* qkv   = (unsigned short*)alloc((size_t)25165824 * 2);  // (4096,6144); V third unused
    unsigned short* Vt    = (unsigned short*)alloc((size_t)8388608 * 2);   // (32,128,2048)
    int* flag             = (int*)alloc(256);
    unsigned short* ctx = hbf; // alias: hidden bf16 dead after QKV GEMM

    hipMemsetAsync(flag, 0, 4, stream);
    scan_mask_k<<<8192, 256, 0, stream>>>(mask, flag);
    convH_k<<<4096, 256, 0, stream>>>(hidden, hbf);
    convT_k<<<dim3(192, 64), 256, 0, stream>>>(Wqkv, wqkvT, 2048, 6144);
    convT_k<<<dim3(64, 64), 256, 0, stream>>>(Wout, woutT, 2048, 2048);
    gemm128_k<0><<<1536, 256, 0, stream>>>(hbf, wqkvT, nullptr, qkv, Vt,
                                           4096, 6144, 2048, 16, 12, 4);
    attn_k<<<512, 256, 0, stream>>>(qkv, Vt, mask, ctx, flag);
    gemm128_k<1><<<512, 256, 0, stream>>>(ctx, woutT, out, nullptr, nullptr,
                                          4096, 2048, 2048, 16, 4, 4);
}

// Round 20
// 289.408 us; speedup vs baseline: 1.1842x; 1.1842x over previous
//
#include <hip/hip_runtime.h>

typedef __attribute__((ext_vector_type(4))) float f32x4;
typedef __attribute__((ext_vector_type(16))) float f32x16;
typedef __attribute__((ext_vector_type(8))) short s16x8;
typedef __attribute__((ext_vector_type(4))) unsigned short u16x4;
typedef __attribute__((ext_vector_type(8))) unsigned short u16x8;

#define DEVINL __device__ __forceinline__

constexpr int Bb = 2;
constexpr int Ss = 2048;
constexpr int Hh = 2048;
constexpr int NH = 16;
constexpr int HD = 128;
constexpr float ATT_SCALE = 0.08838834764831845f;   // 128^-0.5
constexpr float CEXP = ATT_SCALE * 1.44269504089f;  // scale * log2(e)
constexpr float INV_SCALE = 11.313708498984761f;    // 1/scale
constexpr float RAW_THR = 90.50966799f;             // 8/scale (defer-max threshold)

DEVINL unsigned short f2bf(float f) {
    unsigned u = __float_as_uint(f);
    u += 0x7FFFu + ((u >> 16) & 1u);
    return (unsigned short)(u >> 16);
}
DEVINL float bf2f(unsigned short h) { return __uint_as_float(((unsigned)h) << 16); }
DEVINL float fexp2(float x) { return __builtin_amdgcn_exp2f(x); }

// global -> LDS direct (16B per lane). Dest must be linear in lane order.
DEVINL void gl16(const void* g, void* l) {
    __builtin_amdgcn_global_load_lds((const __attribute__((address_space(1))) void*)g,
                                     (__attribute__((address_space(3))) void*)l, 16, 0, 0);
}

// ---------------- mask zero-scan (full coverage: 8192 blocks x 1024 floats) ----------
__global__ void scan_mask_k(const float* __restrict__ m, int* __restrict__ flag) {
    size_t i = ((size_t)blockIdx.x * 256 + threadIdx.x) * 4;
    f32x4 v = *(const f32x4*)(m + i);
    int any = (v[0] != 0.f) || (v[1] != 0.f) || (v[2] != 0.f) || (v[3] != 0.f);
    if (__any(any)) { if ((threadIdx.x & 63) == 0) atomicOr(flag, 1); }
}

// ---------------- fp32 -> bf16 convert (hidden) ----------------
__global__ void convH_k(const float* __restrict__ x, unsigned short* __restrict__ y) {
    size_t i = (size_t)blockIdx.x * 256 + threadIdx.x;
    f32x4 a = *(const f32x4*)(x + i * 8);
    f32x4 b = *(const f32x4*)(x + i * 8 + 4);
    u16x8 o;
    o[0] = f2bf(a[0]); o[1] = f2bf(a[1]); o[2] = f2bf(a[2]); o[3] = f2bf(a[3]);
    o[4] = f2bf(b[0]); o[5] = f2bf(b[1]); o[6] = f2bf(b[2]); o[7] = f2bf(b[3]);
    *(u16x8*)(y + i * 8) = o;
}

// ---------------- fp32 -> bf16 transpose (weights: W[R][C] -> Wt[C][R]) ----------------
__global__ void convT_k(const float* __restrict__ W, unsigned short* __restrict__ Wt,
                        int R, int C) {
    __shared__ float tile[32][33];
    int c0 = blockIdx.x * 32, r0 = blockIdx.y * 32;
    int t = threadIdx.x;
    int rr = t >> 3, cc = (t & 7) * 4;
    f32x4 v = *(const f32x4*)(W + (size_t)(r0 + rr) * C + c0 + cc);
    tile[rr][cc + 0] = v[0]; tile[rr][cc + 1] = v[1];
    tile[rr][cc + 2] = v[2]; tile[rr][cc + 3] = v[3];
    __syncthreads();
    u16x4 o;
    o[0] = f2bf(tile[cc + 0][rr]); o[1] = f2bf(tile[cc + 1][rr]);
    o[2] = f2bf(tile[cc + 2][rr]); o[3] = f2bf(tile[cc + 3][rr]);
    *(u16x4*)(Wt + (size_t)(c0 + rr) * R + r0 + cc) = o;
}

// ====== 128x128 GEMM, BK=64 dbuf, 64KB LDS -> 2 blocks/CU, overlapped staging ======
// 4 waves (2x2), wave 64x64 (4x4 frags 16x16x32). R3-proven LDS layout: 128B rows,
// XOR swizzle byte = row*128 + (col16 ^ ((row&7)<<4)) -> 0 bank conflicts (measured).
// Rectangle XCD swizzle. MODE 0 (QKV): fused RoPE + V written transposed to Vt.
template<int MODE>
__global__ __launch_bounds__(256, 2)
void gemm128_k(const unsigned short* __restrict__ A, const unsigned short* __restrict__ Bt,
               float* __restrict__ Cf, unsigned short* __restrict__ Cb,
               unsigned short* __restrict__ VtOut,
               int M, int N, int K, int rm, int rn, int snx) {
    __shared__ char lds[65536];
    int t = threadIdx.x, w = t >> 6, ln = t & 63, lr = ln & 15, lg = ln >> 4;
    int wr = w >> 1, wc = w & 1;
    int f = blockIdx.x;
    int xcd = f & 7, i0 = f >> 3;
    int mb = (xcd / snx) * rm + i0 % rm;
    int nb = (xcd % snx) * rn + i0 / rm;
    int m0 = mb * 128, n0 = nb * 128;
    const char* Ab = (const char*)A;
    const char* Bbp = (const char*)Bt;

    f32x4 acc[4][4];
#pragma unroll
    for (int i = 0; i < 4; ++i)
#pragma unroll
        for (int j = 0; j < 4; ++j) { acc[i][j][0] = 0.f; acc[i][j][1] = 0.f; acc[i][j][2] = 0.f; acc[i][j][3] = 0.f; }

    // stage K-tile kt into buffer buf: A 16KB + B 16KB, 8 gl16/thread,
    // lane-linear dest, inverse-swizzled source column slot.
    auto STAGE = [&](int buf, int kt) {
        char* dA = lds + buf * 32768;
        char* dB = dA + 16384;
        size_t kb = ((size_t)kt * 64) * 2;
#pragma unroll
        for (int ld = 0; ld < 4; ++ld) {
            int ci = ld * 256 + t;
            int row = ci >> 3, cb = (ci & 7) << 4;
            int sc = cb ^ ((row & 7) << 4);
            gl16(Ab + ((size_t)(m0 + row) * K) * 2 + kb + sc, dA + ci * 16);
            gl16(Bbp + ((size_t)(n0 + row) * K) * 2 + kb + sc, dB + ci * 16);
        }
    };

    const int NT = K >> 6;
    STAGE(0, 0);
    asm volatile("s_waitcnt vmcnt(0)" ::: "memory");
    __builtin_amdgcn_s_barrier();

    for (int kt = 0; kt < NT; ++kt) {
        int cur = kt & 1;
        if (kt + 1 < NT) STAGE(cur ^ 1, kt + 1);   // uniform; hides under compute
        const char* As = lds + cur * 32768;
        const char* Bs = As + 16384;
#pragma unroll
        for (int kc = 0; kc < 2; ++kc) {
            s16x8 af[4], bfr[4];
#pragma unroll
            for (int i = 0; i < 4; ++i) {
                int rowa = wr * 64 + i * 16 + lr;
                af[i] = *(const s16x8*)(As + rowa * 128 + ((kc * 64 + lg * 16) ^ ((rowa & 7) << 4)));
                int rowb = wc * 64 + i * 16 + lr;
                bfr[i] = *(const s16x8*)(Bs + rowb * 128 + ((kc * 64 + lg * 16) ^ ((rowb & 7) << 4)));
            }
            __builtin_amdgcn_s_setprio(1);
#pragma unroll
            for (int i = 0; i < 4; ++i)
#pragma unroll
                for (int j = 0; j < 4; ++j)
                    acc[i][j] = __builtin_amdgcn_mfma_f32_16x16x32_bf16(af[i], bfr[j], acc[i][j], 0, 0, 0);
            __builtin_amdgcn_s_setprio(0);
        }
        // next tile's loads landed under compute; drain + 1 barrier per tile
        asm volatile("s_waitcnt vmcnt(0)" ::: "memory");
        __builtin_amdgcn_s_barrier();
    }

    if (MODE == 0 && n0 >= 4096) {
        // V columns: write transposed directly into Vt[bh=(b*16+h)][d][s]
#pragma unroll
        for (int i = 0; i < 4; ++i)
#pragma unroll
            for (int j = 0; j < 4; ++j) {
                int vcol = n0 - 4096 + wc * 64 + j * 16 + lr;   // 0..2047
                int h = vcol >> 7, d = vcol & 127;
                int gr = m0 + wr * 64 + i * 16 + lg * 4;
                int bb = gr >> 11, si = gr & 2047;
                u16x4 o;
                o[0] = f2bf(acc[i][j][0]); o[1] = f2bf(acc[i][j][1]);
                o[2] = f2bf(acc[i][j][2]); o[3] = f2bf(acc[i][j][3]);
                *(u16x4*)(VtOut + ((size_t)(bb * 16 + h) * 128 + d) * 2048 + si) = o;
            }
        return;
    }

    // fused RoPE (QKV only, n0 < 4096): wc==0 waves hold the rotary pair
    // (j=0 -> d=lr, j=1 -> d=lr+16) of each head's first half.
    if (MODE == 0 && wc == 0) {
        float invf = fexp2((float)lr * -0.83048202372f); // 10000^(-lr/16)
#pragma unroll
        for (int i = 0; i < 4; ++i)
#pragma unroll
            for (int r = 0; r < 4; ++r) {
                int srow = (m0 + wr * 64 + i * 16 + lg * 4 + r) & (Ss - 1);
                float sn, cs;
                sincosf((float)srow * invf, &sn, &cs);
                float x1 = acc[i][0][r], x2 = acc[i][1][r];
                acc[i][0][r] = x1 * cs - x2 * sn;
                acc[i][1][r] = x2 * cs + x1 * sn;
            }
    }

    // epilogue: C/D layout col=l&15, row=(l>>4)*4+r
#pragma unroll
    for (int i = 0; i < 4; ++i)
#pragma unroll
        for (int j = 0; j < 4; ++j)
#pragma unroll
            for (int r = 0; r < 4; ++r) {
                int gr = m0 + wr * 64 + i * 16 + lg * 4 + r;
                int gc = n0 + wc * 64 + j * 16 + lr;
                float vv = acc[i][j][r];
                if (MODE == 1) Cf[(size_t)gr * N + gc] = vv;
                else           Cb[(size_t)gr * N + gc] = f2bf(vv);
            }
}

// ---------------- flash attention (R15/R18: 32x32x16, P in registers via shfl) -------
// 256 blocks (32 bh x 8 qt), 512 thr = 8 waves x 32 q. LDS 64KB (K/V dbuf only).
__global__ __launch_bounds__(512)
void attn_k(const unsigned short* __restrict__ qkv, const unsigned short* __restrict__ Vt,
            const float* __restrict__ mask, unsigned short* __restrict__ ctxb,
            const int* __restrict__ flag) {
    __shared__ char ldsK[2][16384];            // [64 kk][128 d] bf16, 4-bit swizzle
    __shared__ char ldsV[2][16384];            // [128 d][64 kk] bf16, 3-bit swizzle
    int f = blockIdx.x;
    int swzb = (f & 7) * 32 + (f >> 3);        // XCD swizzle: 256 blocks, 32/XCD
    int bh = swzb >> 3, qt = swzb & 7;
    int b = bh >> 4, h = bh & 15;
    int t = threadIdx.x, w = t >> 6, ln = t & 63;
    int q5 = ln & 31, lg5 = ln >> 5;
    int useMask = *flag;
    int qb = qt * 256 + w * 32;                // wave's 32 q-rows
    const char* qkvB = (const char*)qkv;
    const char* VtB = (const char*)Vt;

    auto STAGE = [&](int buf, int kk0s) {
#pragma unroll
        for (int c = 0; c < 2; ++c) {
            int ci = c * 512 + t;
            int krow = ci >> 4, kcb = (ci & 15) << 4;
            gl16(qkvB + (((size_t)(b * Ss + kk0s + krow)) * 6144 + 2048 + h * 128) * 2 + (kcb ^ ((krow & 15) << 4)),
                 ldsK[buf] + ci * 16);
            int vrow = ci >> 3, vcb = (ci & 7) << 4;
            gl16(VtB + (((size_t)(bh * 128 + vrow)) * 2048 + kk0s) * 2 + (vcb ^ ((vrow & 7) << 4)),
                 ldsV[buf] + ci * 16);
        }
    };

    // Q fragments (B-operand): qf[dc] = Q[q=qb+q5][d = dc*16 + lg5*8 + e]
    s16x8 qf[8];
    size_t qrow = ((size_t)(b * Ss + qb + q5)) * 6144 + h * 128;
#pragma unroll
    for (int dc = 0; dc < 8; ++dc) qf[dc] = *(const s16x8*)(qkv + qrow + dc * 16 + lg5 * 8);

    float mr = -3e38f, lsum = 0.f;             // per-lane state for q = qb + q5
    f32x16 ctx[4];
#pragma unroll
    for (int dt = 0; dt < 4; ++dt)
#pragma unroll
        for (int r = 0; r < 16; ++r) ctx[dt][r] = 0.f;
    const float* mrow = mask + (size_t)b * Ss * Ss;

    STAGE(0, 0);
    asm volatile("s_waitcnt vmcnt(0)" ::: "memory");
    __builtin_amdgcn_s_barrier();

    for (int tix = 0; tix < 32; ++tix) {
        int kk0 = tix * 64;
        int cur = tix & 1;
        if (kk0 + 64 < Ss) STAGE(cur ^ 1, kk0 + 64);   // uniform; hides under compute

        f32x16 st[2];
#pragma unroll
        for (int n = 0; n < 2; ++n) {
            f32x16 sacc;
#pragma unroll
            for (int r = 0; r < 16; ++r) sacc[r] = 0.f;
            int krow = n * 32 + q5;
            const char* kb = ldsK[cur] + krow * 256;
            int sw = krow & 15;
            __builtin_amdgcn_s_setprio(1);
#pragma unroll
            for (int dc = 0; dc < 8; ++dc) {
                s16x8 kf = *(const s16x8*)(kb + (((dc * 2 + lg5) ^ sw) << 4));
                sacc = __builtin_amdgcn_mfma_f32_32x32x16_bf16(kf, qf[dc], sacc, 0, 0, 0);
            }
            __builtin_amdgcn_s_setprio(0);
            st[n] = sacc;
        }
        if (useMask) {
#pragma unroll
            for (int n = 0; n < 2; ++n)
#pragma unroll
                for (int r = 0; r < 16; ++r) {
                    int kk = n * 32 + (r & 3) + 8 * (r >> 2) + 4 * lg5;
                    st[n][r] += mrow[(size_t)(qb + q5) * Ss + kk0 + kk] * INV_SCALE;
                }
        }
        float pmax = st[0][0];
#pragma unroll
        for (int n = 0; n < 2; ++n)
#pragma unroll
            for (int r = 0; r < 16; ++r) pmax = fmaxf(pmax, st[n][r]);
        pmax = fmaxf(pmax, __shfl_xor(pmax, 32));
        bool need = pmax > mr + RAW_THR;
        if (__any(need)) {
            float mn = fmaxf(mr, pmax);
            float al = fexp2((mr - mn) * CEXP);
            mr = mn;
            lsum *= al;
#pragma unroll
            for (int dt = 0; dt < 4; ++dt)
#pragma unroll
                for (int r = 0; r < 16; ++r)
                    ctx[dt][r] *= __shfl(al, (r & 3) + 8 * (r >> 2) + 4 * lg5);
        }
        float mC = mr * CEXP;
        float rs = 0.f;
#pragma unroll
        for (int n = 0; n < 2; ++n)
#pragma unroll
            for (int r = 0; r < 16; ++r) {
                float p = fexp2(st[n][r] * CEXP - mC);
                rs += p;
                st[n][r] = p;
            }
        rs += __shfl_xor(rs, 32);
        lsum += rs;
        // P -> A-fragments in registers (no LDS roundtrip): pack pairs, exchange
        // complementary kk-half via shfl_xor(32), select by lg5.
        s16x8 paf[4];
#pragma unroll
        for (int c = 0; c < 4; ++c) {
            const f32x16 sv = st[c >> 1];
            const int cc = (c & 1) * 8;
            unsigned loA = (unsigned)f2bf(sv[cc + 0]) | ((unsigned)f2bf(sv[cc + 1]) << 16);
            unsigned loB = (unsigned)f2bf(sv[cc + 2]) | ((unsigned)f2bf(sv[cc + 3]) << 16);
            unsigned hiA = (unsigned)f2bf(sv[cc + 4]) | ((unsigned)f2bf(sv[cc + 5]) << 16);
            unsigned hiB = (unsigned)f2bf(sv[cc + 6]) | ((unsigned)f2bf(sv[cc + 7]) << 16);
            unsigned sendA = lg5 ? loA : hiA;
            unsigned sendB = lg5 ? loB : hiB;
            unsigned recvA = (unsigned)__shfl_xor((int)sendA, 32);
            unsigned recvB = (unsigned)__shfl_xor((int)sendB, 32);
            union { s16x8 v; unsigned u[4]; } pu;
            pu.u[0] = lg5 ? recvA : loA;
            pu.u[1] = lg5 ? recvB : loB;
            pu.u[2] = lg5 ? hiA : recvA;
            pu.u[3] = lg5 ? hiB : recvB;
            paf[c] = pu.v;
        }
        // PV: ctx[q][d] += P[q][kk] * V[kk][d]
#pragma unroll
        for (int dt = 0; dt < 4; ++dt) {
            int vrow = dt * 32 + q5;
            const char* vb = ldsV[cur] + vrow * 128;
            int swv = vrow & 7;
            __builtin_amdgcn_s_setprio(1);
#pragma unroll
            for (int c = 0; c < 4; ++c) {
                s16x8 vf = *(const s16x8*)(vb + (((c * 2 + lg5) ^ swv) << 4));
                ctx[dt] = __builtin_amdgcn_mfma_f32_32x32x16_bf16(paf[c], vf, ctx[dt], 0, 0, 0);
            }
            __builtin_amdgcn_s_setprio(0);
        }
        asm volatile("s_waitcnt vmcnt(0)" ::: "memory");
        __builtin_amdgcn_s_barrier();
    }
    // epilogue: divide by lsum[q_r], write ctx bf16 (lanes 0..31 = consecutive d)
#pragma unroll
    for (int r = 0; r < 16; ++r) {
        int qr = (r & 3) + 8 * (r >> 2) + 4 * lg5;
        float li = 1.f / __shfl(lsum, qr);
        size_t base = ((size_t)(b * Ss + qb + qr)) * Hh + h * 128 + q5;
#pragma unroll
        for (int dt = 0; dt < 4; ++dt)
            ctxb[base + dt * 32] = f2bf(ctx[dt][r] * li);
    }
}

extern "C" void kernel_launch(void* const* d_in, const int* in_sizes, int n_in,
                              void* d_out, int out_size, void* d_ws, size_t ws_size,
                              hipStream_t stream) {
    (void)in_sizes; (void)n_in; (void)out_size; (void)ws_size;
    const float* hidden = (const float*)d_in[0];
    const float* mask   = (const float*)d_in[1];
    const float* Wqkv   = (const float*)d_in[2];
    const float* Wout   = (const float*)d_in[3];
    float* out = (float*)d_out;

    char* ws = (char*)d_ws;
    size_t off = 0;
    auto alloc = [&](size_t bytes) { char* p = ws + off; off += (bytes + 255) & ~(size_t)255; return p; };
    unsigned short* hbf   = (unsigned short*)alloc((size_t)8388608 * 2);   // hidden bf16; later aliased as ctx
    unsigned short* wqkvT = (unsigned short*)alloc((size_t)12582912 * 2);  // (6144,2048)
    unsigned short* woutT = (unsigned short*)alloc((size_t)4194304 * 2);   // (2048,2048)
    unsigned short* qkv   = (unsigned short*)alloc((size_t)25165824 * 2);  // (4096,6144); V third unused
    unsigned short* Vt    = (unsigned short*)alloc((size_t)8388608 * 2);   // (32,128,2048)
    int* flag             = (int*)alloc(256);
    unsigned short* ctx = hbf; // alias: hidden bf16 dead after QKV GEMM

    hipMemsetAsync(flag, 0, 4, stream);
    scan_mask_k<<<8192, 256, 0, stream>>>(mask, flag);
    convH_k<<<4096, 256, 0, stream>>>(hidden, hbf);
    convT_k<<<dim3(192, 64), 256, 0, stream>>>(Wqkv, wqkvT, 2048, 6144);
    convT_k<<<dim3(64, 64), 256, 0, stream>>>(Wout, woutT, 2048, 2048);
    gemm128_k<0><<<1536, 256, 0, stream>>>(hbf, wqkvT, nullptr, qkv, Vt,
                                           4096, 6144, 2048, 16, 12, 4);
    attn_k<<<256, 512, 0, stream>>>(qkv, Vt, mask, ctx, flag);
    gemm128_k<1><<<512, 256, 0, stream>>>(ctx, woutT, out, nullptr, nullptr,
                                          4096, 2048, 2048, 16, 4, 4);
}